// Round 3
// baseline (123.301 us; speedup 1.0000x reference)
//
#include <hip/hip_runtime.h>
#include <hip/hip_cooperative_groups.h>

namespace cg = cooperative_groups;

// DocumentBertScoringLoss: loss = MSE + MR + SIM over B=8192 fp32 vectors.
// MR term == mean over all (m,n) of max(0, 0.1 - |p_m - p_n|) (verified r1).
// Single cooperative kernel: pairwise + linear partials, grid.sync(),
// block (0,0) combines in fixed order. No memset node (r2 lesson: a 4-byte
// fillBufferAligned node costs ~39 us), no atomics, fully deterministic.

#define B_N 8192
#define THREADS 256
#define M_PER_THREAD 2
#define MB (THREADS * M_PER_THREAD)   // 512 m-rows per block
#define NXB (B_N / MB)                // 16 m-chunks
#define CHUNK 256                     // n's staged in LDS per block
#define NYB (B_N / CHUNK)             // 32 n-chunks
#define NBLOCKS (NXB * NYB)           // 512 blocks = 2/CU

__device__ __forceinline__ float block_reduce_sum(float v, float* sbuf) {
    #pragma unroll
    for (int off = 32; off > 0; off >>= 1)
        v += __shfl_down(v, off, 64);
    const int lane = threadIdx.x & 63;
    const int wave = threadIdx.x >> 6;
    if (lane == 0) sbuf[wave] = v;
    __syncthreads();
    if (threadIdx.x == 0) {
        float s = 0.f;
        #pragma unroll
        for (int w = 0; w < THREADS / 64; ++w) s += sbuf[w];
        sbuf[0] = s;
    }
    __syncthreads();
    const float r = sbuf[0];
    __syncthreads();   // sbuf reusable by caller afterwards
    return r;
}

__global__ void __launch_bounds__(THREADS)
fused_loss_kernel(const float* __restrict__ p, const float* __restrict__ g,
                  float* __restrict__ pairPartial,   // [NBLOCKS]
                  float* __restrict__ linPartial,    // [NXB*4]
                  float* __restrict__ out) {
    __shared__ float s_n[CHUNK];
    __shared__ float sbuf[THREADS / 64];

    const int tid = threadIdx.x;
    const int bx = blockIdx.x, by = blockIdx.y;
    const int m0 = bx * MB + tid;          // coalesced
    const int m1 = m0 + THREADS;

    s_n[tid] = p[by * CHUNK + tid];
    const float pm0 = p[m0];
    const float pm1 = p[m1];
    __syncthreads();

    // 8 independent accumulators; ds_read_b128 broadcast (uniform addr).
    float a00 = 0.f, a01 = 0.f, a02 = 0.f, a03 = 0.f;
    float a10 = 0.f, a11 = 0.f, a12 = 0.f, a13 = 0.f;
    const float4* s4 = (const float4*)s_n;
    #pragma unroll 4
    for (int j = 0; j < CHUNK / 4; ++j) {
        const float4 v = s4[j];
        a00 += fmaxf(0.f, 0.1f - fabsf(pm0 - v.x));
        a01 += fmaxf(0.f, 0.1f - fabsf(pm0 - v.y));
        a02 += fmaxf(0.f, 0.1f - fabsf(pm0 - v.z));
        a03 += fmaxf(0.f, 0.1f - fabsf(pm0 - v.w));
        a10 += fmaxf(0.f, 0.1f - fabsf(pm1 - v.x));
        a11 += fmaxf(0.f, 0.1f - fabsf(pm1 - v.y));
        a12 += fmaxf(0.f, 0.1f - fabsf(pm1 - v.z));
        a13 += fmaxf(0.f, 0.1f - fabsf(pm1 - v.w));
    }
    const float acc = ((a00 + a01) + (a02 + a03)) + ((a10 + a11) + (a12 + a13));
    const float s = block_reduce_sum(acc, sbuf);
    if (tid == 0) pairPartial[by * NXB + bx] = s;

    if (by == 0) {                          // block-uniform branch
        const float gv0 = g[m0], gv1 = g[m1];
        const float d0 = pm0 - gv0, d1 = pm1 - gv1;
        float sq  = d0 * d0 + d1 * d1;
        float dot = pm0 * gv0 + pm1 * gv1;
        float npp = pm0 * pm0 + pm1 * pm1;
        float ngg = gv0 * gv0 + gv1 * gv1;
        sq  = block_reduce_sum(sq, sbuf);
        dot = block_reduce_sum(dot, sbuf);
        npp = block_reduce_sum(npp, sbuf);
        ngg = block_reduce_sum(ngg, sbuf);
        if (tid == 0) {
            linPartial[bx * 4 + 0] = sq;
            linPartial[bx * 4 + 1] = dot;
            linPartial[bx * 4 + 2] = npp;
            linPartial[bx * 4 + 3] = ngg;
        }
    }

    // Make partial stores device-visible, then grid-wide sync.
    __threadfence();
    cg::this_grid().sync();

    if (bx != 0 || by != 0) return;

    // Block (0,0) combines everything in a fixed order -> deterministic.
    float mr = 0.f;
    for (int i = tid; i < NBLOCKS; i += THREADS)
        mr += pairPartial[i];
    mr = block_reduce_sum(mr, sbuf);

    float lv[4];
    #pragma unroll
    for (int k = 0; k < 4; ++k) {
        float v = 0.f;
        if (tid < NXB) v = linPartial[tid * 4 + k];
        lv[k] = block_reduce_sum(v, sbuf);
    }

    if (tid == 0) {
        const float mse = lv[0] / (float)B_N;
        const float mrm = mr / ((float)B_N * (float)B_N);
        const float denom = fmaxf(sqrtf(lv[2]) * sqrtf(lv[3]), 1e-8f);
        const float sim = 1.f - lv[1] / denom;
        out[0] = mse + mrm + sim;           // alpha = beta = gamma = 1
    }
}

extern "C" void kernel_launch(void* const* d_in, const int* in_sizes, int n_in,
                              void* d_out, int out_size, void* d_ws, size_t ws_size,
                              hipStream_t stream) {
    const float* p = (const float*)d_in[0];
    const float* g = (const float*)d_in[1];
    float* pairPartial = (float*)d_ws;            // 512 floats, all rewritten each call
    float* linPartial  = (float*)d_ws + NBLOCKS;  // 64 floats, all rewritten each call
    float* out = (float*)d_out;

    dim3 grid(NXB, NYB);
    dim3 block(THREADS);
    void* args[] = {(void*)&p, (void*)&g, (void*)&pairPartial,
                    (void*)&linPartial, (void*)&out};
    hipLaunchCooperativeKernel((const void*)fused_loss_kernel,
                               grid, block, args, 0, stream);
}

// Round 4
// 15.626 us; speedup vs baseline: 7.8909x; 7.8909x over previous
//
#include <hip/hip_runtime.h>

// DocumentBertScoringLoss: loss = MSE + MR + SIM over B=8192 fp32 vectors.
// MR term == mean over all (m,n) of max(0, 0.1 - |p_m - p_n|) (verified r1).
//
// Structure history (measured):
//   r1 two-kernel scalar-LDS pairwise: 18.4 us
//   r2 + 4-byte memset node: +39 us (fillBufferAligned fixed cost) -> 27.4
//   r3 cooperative grid.sync(): 104 us/dispatch -> 123. DEAD END.
// This round: two plain kernels (no memset/atomics/coop) + vectorized
// pairwise loop (float4 LDS broadcast, 8 accumulators, 2 m-rows/thread).

#define B_N 8192
#define THREADS 256
#define M_PER_THREAD 2
#define MB (THREADS * M_PER_THREAD)   // 512 m-rows per block
#define NXB (B_N / MB)                // 16 m-chunks
#define CHUNK 128                     // n's staged in LDS per block
#define NYB (B_N / CHUNK)             // 64 n-chunks
#define NBLOCKS (NXB * NYB)           // 1024 blocks = 4/CU -> 16 waves/CU

__device__ __forceinline__ float block_reduce_sum(float v, float* sbuf) {
    #pragma unroll
    for (int off = 32; off > 0; off >>= 1)
        v += __shfl_down(v, off, 64);
    const int lane = threadIdx.x & 63;
    const int wave = threadIdx.x >> 6;
    if (lane == 0) sbuf[wave] = v;
    __syncthreads();
    if (threadIdx.x == 0) {
        float s = 0.f;
        #pragma unroll
        for (int w = 0; w < THREADS / 64; ++w) s += sbuf[w];
        sbuf[0] = s;
    }
    __syncthreads();
    const float r = sbuf[0];
    __syncthreads();   // sbuf reusable by caller afterwards
    return r;
}

__global__ void __launch_bounds__(THREADS)
pairwise_kernel(const float* __restrict__ p, const float* __restrict__ g,
                float* __restrict__ pairPartial,   // [NBLOCKS]
                float* __restrict__ linPartial) {  // [NXB*4]
    __shared__ float s_n[CHUNK];
    __shared__ float sbuf[THREADS / 64];

    const int tid = threadIdx.x;
    const int bx = blockIdx.x, by = blockIdx.y;
    const int m0 = bx * MB + tid;          // coalesced
    const int m1 = m0 + THREADS;

    if (tid < CHUNK) s_n[tid] = p[by * CHUNK + tid];
    const float pm0 = p[m0];
    const float pm1 = p[m1];
    __syncthreads();

    // 8 independent accumulators; ds_read_b128 broadcast (uniform addr, no conflicts).
    float a00 = 0.f, a01 = 0.f, a02 = 0.f, a03 = 0.f;
    float a10 = 0.f, a11 = 0.f, a12 = 0.f, a13 = 0.f;
    const float4* s4 = (const float4*)s_n;
    #pragma unroll 4
    for (int j = 0; j < CHUNK / 4; ++j) {
        const float4 v = s4[j];
        a00 += fmaxf(0.f, 0.1f - fabsf(pm0 - v.x));
        a01 += fmaxf(0.f, 0.1f - fabsf(pm0 - v.y));
        a02 += fmaxf(0.f, 0.1f - fabsf(pm0 - v.z));
        a03 += fmaxf(0.f, 0.1f - fabsf(pm0 - v.w));
        a10 += fmaxf(0.f, 0.1f - fabsf(pm1 - v.x));
        a11 += fmaxf(0.f, 0.1f - fabsf(pm1 - v.y));
        a12 += fmaxf(0.f, 0.1f - fabsf(pm1 - v.z));
        a13 += fmaxf(0.f, 0.1f - fabsf(pm1 - v.w));
    }
    const float acc = ((a00 + a01) + (a02 + a03)) + ((a10 + a11) + (a12 + a13));
    const float s = block_reduce_sum(acc, sbuf);
    if (tid == 0) pairPartial[by * NXB + bx] = s;

    if (by == 0) {                          // block-uniform branch
        const float gv0 = g[m0], gv1 = g[m1];
        const float d0 = pm0 - gv0, d1 = pm1 - gv1;
        float sq  = d0 * d0 + d1 * d1;
        float dot = pm0 * gv0 + pm1 * gv1;
        float npp = pm0 * pm0 + pm1 * pm1;
        float ngg = gv0 * gv0 + gv1 * gv1;
        sq  = block_reduce_sum(sq, sbuf);
        dot = block_reduce_sum(dot, sbuf);
        npp = block_reduce_sum(npp, sbuf);
        ngg = block_reduce_sum(ngg, sbuf);
        if (tid == 0) {
            linPartial[bx * 4 + 0] = sq;
            linPartial[bx * 4 + 1] = dot;
            linPartial[bx * 4 + 2] = npp;
            linPartial[bx * 4 + 3] = ngg;
        }
    }
}

__global__ void __launch_bounds__(THREADS)
finalize_kernel(const float* __restrict__ pairPartial,
                const float* __restrict__ linPartial,
                float* __restrict__ out) {
    __shared__ float sbuf[THREADS / 64];

    float mr = 0.f;
    #pragma unroll
    for (int k = 0; k < NBLOCKS / THREADS; ++k)
        mr += pairPartial[k * THREADS + threadIdx.x];
    mr = block_reduce_sum(mr, sbuf);

    float lv[4];
    #pragma unroll
    for (int k = 0; k < 4; ++k) {
        float v = 0.f;
        if (threadIdx.x < NXB) v = linPartial[threadIdx.x * 4 + k];
        lv[k] = block_reduce_sum(v, sbuf);
    }

    if (threadIdx.x == 0) {
        const float mse = lv[0] / (float)B_N;
        const float mrm = mr / ((float)B_N * (float)B_N);
        const float denom = fmaxf(sqrtf(lv[2]) * sqrtf(lv[3]), 1e-8f);
        const float sim = 1.f - lv[1] / denom;
        out[0] = mse + mrm + sim;           // alpha = beta = gamma = 1
    }
}

extern "C" void kernel_launch(void* const* d_in, const int* in_sizes, int n_in,
                              void* d_out, int out_size, void* d_ws, size_t ws_size,
                              hipStream_t stream) {
    const float* p = (const float*)d_in[0];
    const float* g = (const float*)d_in[1];
    float* pairPartial = (float*)d_ws;            // 1024 floats, all rewritten each call
    float* linPartial  = (float*)d_ws + NBLOCKS;  // 64 floats, all rewritten each call

    dim3 grid(NXB, NYB);
    pairwise_kernel<<<grid, THREADS, 0, stream>>>(p, g, pairPartial, linPartial);
    finalize_kernel<<<1, THREADS, 0, stream>>>(pairPartial, linPartial, (float*)d_out);
}